// Round 8
// baseline (440.596 us; speedup 1.0000x reference)
//
#include <hip/hip_runtime.h>
#include <hip/hip_bf16.h>
#include <stdint.h>

#define D_MODEL 1024
#define NHEAD   16
#define BATCH   4
#define SEQ     2048
#define M_TOK   (BATCH*SEQ)   // 8192

// 0.125 * log2(e) folded into the Q projection
#define QSCALE  0.18033688011112042f

typedef __attribute__((ext_vector_type(8))) short bf16x8;
typedef __attribute__((ext_vector_type(4))) float f32x4;

static __device__ __forceinline__ unsigned short f2b(float x) {
  union { float f; unsigned int u; } a; a.f = x;
  unsigned int u = a.u;
  u += 0x7FFFu + ((u >> 16) & 1u);   // RNE
  return (unsigned short)(u >> 16);
}

static __device__ __forceinline__ unsigned int cvt_pk_bf16(float lo, float hi) {
  unsigned int r;
  asm("v_cvt_pk_bf16_f32 %0, %1, %2" : "=v"(r) : "v"(lo), "v"(hi));
  return r;
}

typedef const __attribute__((address_space(1))) unsigned int g_u32;
typedef __attribute__((address_space(3))) unsigned int l_u32;
static __device__ __forceinline__ void glds16(const void* g, void* l) {
  __builtin_amdgcn_global_load_lds((g_u32*)g, (l_u32*)l, 16, 0, 0);
}

// ---------------- weight transpose-cast (4 weights merged): W[K][N] f32 -> Wt[N][K] bf16 ----------------
__global__ void k_wtrans(const float* __restrict__ w0, const float* __restrict__ w1,
                         const float* __restrict__ w2, const float* __restrict__ w3,
                         unsigned short* __restrict__ wt) {
  __shared__ float tile[32][33];
  int z = blockIdx.z;
  const float* w = (z == 0) ? w0 : (z == 1) ? w1 : (z == 2) ? w2 : w3;
  unsigned short* out = wt + (size_t)z * D_MODEL * D_MODEL;
  int n0 = blockIdx.x * 32, k0 = blockIdx.y * 32;
  int tx = threadIdx.x;   // 0..31
  int ty = threadIdx.y;   // 0..7
  #pragma unroll
  for (int j = 0; j < 4; ++j)
    tile[ty + 8*j][tx] = w[(long)(k0 + ty + 8*j)*D_MODEL + n0 + tx];
  __syncthreads();
  #pragma unroll
  for (int j = 0; j < 4; ++j)
    out[(long)(n0 + ty + 8*j)*D_MODEL + k0 + tx] = f2b(tile[tx][ty + 8*j]);
}

// ---------------- GEMM core (m97 structure + XOR-swizzled LDS + 2-phase dbuf) ----------------
// A_F32: A is fp32, staged raw (16B chunks, chunk^(row&7) swizzle), converted to bf16
//        between LDS read and MFMA.  Else A is bf16 (chunk^(row&3) swizzle).
// B is always bf16 [N][K] (chunk^(row&3) swizzle).
template<int A_F32, int OUT_BF16>
static __device__ __forceinline__ void gemm_body(
    const void* __restrict__ Aptr,
    const unsigned short* __restrict__ Bt,
    const float* __restrict__ bias,
    void* __restrict__ Cout,
    int Ndim, int Kdim, float scale,
    void* As0, void* As1, unsigned short* Bs0, unsigned short* Bs1,
    long m0, long n0)
{
  const int tid  = threadIdx.x;
  const int lane = tid & 63;
  const int w    = tid >> 6;
  const int wr   = w >> 1, wc = w & 1;
  const int l15  = lane & 15, lg = lane >> 4;

  f32x4 acc[4][4];
  #pragma unroll
  for (int i = 0; i < 4; ++i)
    #pragma unroll
    for (int j = 0; j < 4; ++j)
      #pragma unroll
      for (int c = 0; c < 4; ++c) acc[i][j][c] = 0.f;

  // staging lane decompositions
  const int r8 = lane >> 3, c8s = (lane & 7) ^ (r8 & 7);   // fp32 A: 8 rows x 8 chunks
  const int r4 = lane >> 2, c4s = (lane & 3) ^ (r4 & 3);   // bf16:  16 rows x 4 chunks

#define STAGEK(kt_, buf_) do {                                               \
    void* As_ = (buf_) ? As1 : As0;                                          \
    unsigned short* Bs_ = (buf_) ? Bs1 : Bs0;                                \
    if (A_F32) {                                                             \
      const float* Af = (const float*)Aptr;                                  \
      _Pragma("unroll")                                                      \
      for (int j = 0; j < 4; ++j)                                            \
        glds16(Af + (m0 + w*32 + j*8 + r8) * Kdim + (kt_) + c8s*4,           \
               (float*)As_ + (w*32 + j*8) * 32);                             \
    } else {                                                                 \
      const unsigned short* Ab = (const unsigned short*)Aptr;                \
      _Pragma("unroll")                                                      \
      for (int j = 0; j < 2; ++j)                                            \
        glds16(Ab + (m0 + w*32 + j*16 + r4) * Kdim + (kt_) + c4s*8,          \
               (unsigned short*)As_ + (w*32 + j*16) * 32);                   \
    }                                                                        \
    _Pragma("unroll")                                                        \
    for (int j = 0; j < 2; ++j)                                              \
      glds16(Bt + (n0 + w*32 + j*16 + r4) * Kdim + (kt_) + c4s*8,            \
             Bs_ + (w*32 + j*16) * 32);                                      \
  } while (0)

  STAGEK(0, 0);

  #pragma unroll 2
  for (int kt = 0, bu = 0; kt < Kdim; kt += 32, bu ^= 1) {
    __syncthreads();                         // buf[bu] staged; prev-iter reads done
    if (kt + 32 < Kdim) STAGEK(kt + 32, bu ^ 1);
    const void* As_ = bu ? As1 : As0;
    const unsigned short* Bs_ = bu ? Bs1 : Bs0;

    bf16x8 af[4], bfr[4];
    #pragma unroll
    for (int m = 0; m < 4; ++m) {
      if (A_F32) {
        const float* base = (const float*)As_ + (wr*64 + m*16 + l15) * 32;
        f32x4 lo = *(const f32x4*)(base + (((2*lg    ) ^ (l15 & 7)) * 4));
        f32x4 hi = *(const f32x4*)(base + (((2*lg + 1) ^ (l15 & 7)) * 4));
        union { bf16x8 v; unsigned int u[4]; } tmpu;
        tmpu.u[0] = cvt_pk_bf16(lo[0], lo[1]);
        tmpu.u[1] = cvt_pk_bf16(lo[2], lo[3]);
        tmpu.u[2] = cvt_pk_bf16(hi[0], hi[1]);
        tmpu.u[3] = cvt_pk_bf16(hi[2], hi[3]);
        af[m] = tmpu.v;
      } else {
        af[m] = *(const bf16x8*)((const unsigned short*)As_ +
                 (wr*64 + m*16 + l15) * 32 + ((lg ^ (l15 & 3)) * 8));
      }
    }
    #pragma unroll
    for (int n = 0; n < 4; ++n)
      bfr[n] = *(const bf16x8*)&Bs_[(wc*64 + n*16 + l15) * 32 + ((lg ^ (l15 & 3)) * 8)];
    #pragma unroll
    for (int m = 0; m < 4; ++m)
      #pragma unroll
      for (int n = 0; n < 4; ++n)
        acc[m][n] = __builtin_amdgcn_mfma_f32_16x16x32_bf16(af[m], bfr[n], acc[m][n], 0, 0, 0);
  }
#undef STAGEK

  #pragma unroll
  for (int m = 0; m < 4; ++m) {
    #pragma unroll
    for (int r = 0; r < 4; ++r) {
      long row = m0 + wr*64 + m*16 + lg*4 + r;
      #pragma unroll
      for (int n = 0; n < 4; ++n) {
        long col = n0 + wc*64 + n*16 + l15;
        float v = (acc[m][n][r] + bias[col]) * scale;
        if (OUT_BF16) ((unsigned short*)Cout)[row * Ndim + col] = f2b(v);
        else          ((float*)Cout)[row * Ndim + col] = v;
      }
    }
  }
}

// XCD-clustering remap for an (8 n-blocks) x (64 m-rows) grid:
// all 8 n-blocks of one m-row get the same lb%8 -> same XCD -> A-panel L2-shared.
static __device__ __forceinline__ void xcd_remap_8x64(int& m, int& n) {
  int lb = blockIdx.x + (blockIdx.y << 3);   // 0..511
  int xcd = lb & 7, i = lb >> 3;             // i: 0..63
  m = (xcd << 3) | (i >> 3);                 // 8 m-rows per XCD
  n = i & 7;
}

// merged Q/K/V projection from raw fp32 inputs: blockIdx.z selects which
__global__ __launch_bounds__(256) void k_gemm_qkv(
    const float* __restrict__ q, const float* __restrict__ k, const float* __restrict__ v,
    const unsigned short* __restrict__ wt,
    const float* __restrict__ b_q, const float* __restrict__ b_k, const float* __restrict__ b_v,
    unsigned short* __restrict__ Qp, unsigned short* __restrict__ Kp, unsigned short* __restrict__ Vp)
{
  __shared__ float          Asf[2][128*32];  // 32 KB
  __shared__ unsigned short Bs [2][128*32];  // 16 KB
  int z = blockIdx.z;
  const float* A           = (z == 0) ? q : (z == 1) ? k : v;
  const unsigned short* Bt = wt + (size_t)z * D_MODEL * D_MODEL;
  const float* bias        = (z == 0) ? b_q : (z == 1) ? b_k : b_v;
  unsigned short* Cout     = (z == 0) ? Qp : (z == 1) ? Kp : Vp;
  float scale              = (z == 0) ? QSCALE : 1.f;
  int m, n; xcd_remap_8x64(m, n);
  gemm_body<1, 1>(A, Bt, bias, Cout, D_MODEL, D_MODEL, scale,
                  Asf[0], Asf[1], Bs[0], Bs[1], (long)m * 128, (long)n * 128);
}

__global__ __launch_bounds__(256) void k_gemm_out(
    const unsigned short* __restrict__ A, const unsigned short* __restrict__ Bt,
    const float* __restrict__ bias, float* __restrict__ Cout)
{
  __shared__ unsigned short As16[2][128*32]; // 16 KB
  __shared__ unsigned short Bs  [2][128*32]; // 16 KB
  int m, n; xcd_remap_8x64(m, n);
  gemm_body<0, 0>(A, Bt, bias, Cout, D_MODEL, D_MODEL, 1.f,
                  As16[0], As16[1], Bs[0], Bs[1], (long)m * 128, (long)n * 128);
}

// ---------------- V transpose per head, with kv permuted within 32-blocks ----------------
// Vt[(bh*64+d)][t0 + p] = Vp[b, kv = t0 + perm(p), h*64+d],
// perm(p) = (p&32) + 16*((p>>2)&1) + 4*((p>>3)&3) + (p&3)  — matches PV fragment order.
__global__ void k_vtrans(const unsigned short* __restrict__ Vp, unsigned short* __restrict__ Vt) {
  __shared__ unsigned short tile[64][72];
  int bh = blockIdx.y;
  int b = bh >> 4, h = bh & 15;
  int t0 = blockIdx.x * 64;
  int tid = threadIdx.x;
  #pragma unroll
  for (int p = 0; p < 2; ++p) {
    int idx = p*256 + tid;
    int tr = idx >> 3, c8 = (idx & 7) * 8;
    *(int4*)&tile[tr][c8] =
        *(const int4*)&Vp[((long)b*SEQ + t0 + tr)*D_MODEL + h*64 + c8];
  }
  __syncthreads();
  #pragma unroll
  for (int p = 0; p < 2; ++p) {
    int idx = p*256 + tid;
    int d = idx >> 3, c8 = (idx & 7) * 8;
    unsigned short tmp[8];
    #pragma unroll
    for (int j = 0; j < 8; ++j) {
      int pos = c8 + j;
      int src = (pos & 32) + (((pos >> 2) & 1) << 4) + (((pos >> 3) & 3) << 2) + (pos & 3);
      tmp[j] = tile[src][d];
    }
    *(int4*)&Vt[((long)bh*64 + d)*SEQ + t0 + c8] = *(int4*)tmp;
  }
}

// ---------------- flash attention: swapped QK^T, lane-local P->PV, dbuf glds16 staging ----------------
// Q pre-scaled by QSCALE -> S directly in exp2 domain.
__global__ __launch_bounds__(256) void k_attn(
    const unsigned short* __restrict__ Qp,
    const unsigned short* __restrict__ Kp,
    const unsigned short* __restrict__ Vt,
    unsigned short* __restrict__ Ao)
{
  __shared__ unsigned short KV[2][2][64*64];   // [buf][K/V][row*64+col], 32 KB total
  const int tid = threadIdx.x;
  const int lane = tid & 63;
  const int w = tid >> 6;
  // XCD-cluster remap: the 16 q-blocks of one (b,h) share K/V (1 MB) -> same XCD;
  // 8 heads/XCD x (K+V 1 MB) = 4 MB = L2 size.
  int lb = blockIdx.x + (blockIdx.y << 4);     // 0..1023
  int xcd = lb & 7, li = lb >> 3;              // li: 0..127
  const int bh = (xcd << 3) | (li >> 4);       // 0..63
  const int qblk = li & 15;
  const int b = bh >> 4, h = bh & 15;
  const int q0 = qblk * 128;
  const int l15 = lane & 15, lg = lane >> 4;
  const int swz = l15 & 7;

  // Q fragments (B-operand of swapped QK^T): q row = w*32 + qb*16 + l15
  bf16x8 qf[2][2];
  #pragma unroll
  for (int qb = 0; qb < 2; ++qb) {
    const long qrow = (long)b*SEQ + q0 + w*32 + qb*16 + l15;
    #pragma unroll
    for (int kb = 0; kb < 2; ++kb)
      qf[qb][kb] = *(const bf16x8*)&Qp[qrow*D_MODEL + h*64 + kb*32 + lg*8];
  }

  f32x4 acc[2][4];
  float mrun[2], lrun[2];
  #pragma unroll
  for (int qb = 0; qb < 2; ++qb) {
    #pragma unroll
    for (int nb = 0; nb < 4; ++nb)
      #pragma unroll
      for (int c = 0; c < 4; ++c) acc[qb][nb][c] = 0.f;
    mrun[qb] = -1e30f; lrun[qb] = 0.f;
  }

  // glds16 staging: wave w stages rows w*16..w*16+15; lane i -> row +(i>>3), phys chunk i&7,
  // source chunk (i&7)^((i>>3)&7)  (LDS slot (row,p) holds global chunk p^(row&7))
  const int sr = lane >> 3;
  const int sc = (lane & 7) ^ (sr & 7);
  const unsigned short* Kg = Kp + ((long)b*SEQ + w*16 + sr) * D_MODEL + h*64 + sc*8;
  const unsigned short* Vg = Vt + ((long)bh*64 + w*16 + sr) * SEQ + sc*8;

  const int NT = SEQ / 64;

#define STAGE(t, buf) do {                                              \
    unsigned short* Kb_ = &KV[(buf)][0][0] + w*16*64;                   \
    unsigned short* Vb_ = &KV[(buf)][1][0] + w*16*64;                   \
    glds16(Kg + (long)(t)*64*D_MODEL,                   Kb_);           \
    glds16(Kg + (long)(t)*64*D_MODEL + 8L*D_MODEL,      Kb_ + 8*64);    \
    glds16(Vg + (t)*64,                                 Vb_);           \
    glds16(Vg + (t)*64 + 8*SEQ,                         Vb_ + 8*64);    \
  } while (0)

  STAGE(0, 0);

  for (int t = 0; t < NT; ++t) {
    __syncthreads();                 // drains vmcnt -> buf[t&1] staged; all waves past t-1 reads
    if (t + 1 < NT) STAGE(t + 1, (t + 1) & 1);
    const unsigned short* Kb = &KV[t & 1][0][0];
    const unsigned short* Vb = &KV[t & 1][1][0];

    // --- QK^T (swapped): s[qb][nb][r] = S[q=l15][k=16nb+4lg+r]
    f32x4 s[2][4];
    #pragma unroll
    for (int qb = 0; qb < 2; ++qb)
      #pragma unroll
      for (int nb = 0; nb < 4; ++nb)
        #pragma unroll
        for (int c = 0; c < 4; ++c) s[qb][nb][c] = 0.f;
    #pragma unroll
    for (int nb = 0; nb < 4; ++nb) {
      #pragma unroll
      for (int kb = 0; kb < 2; ++kb) {
        bf16x8 kf = *(const bf16x8*)&Kb[(nb*16 + l15)*64 + (((kb*4 + lg) ^ swz) * 8)];
        s[0][nb] = __builtin_amdgcn_mfma_f32_16x16x32_bf16(kf, qf[0][kb], s[0][nb], 0, 0, 0);
        s[1][nb] = __builtin_amdgcn_mfma_f32_16x16x32_bf16(kf, qf[1][kb], s[1][nb], 0, 0, 0);
      }
    }

    // --- softmax (exp2 domain) + lane-local pack into PV A-fragments
    bf16x8 pa[2][2];
    #pragma unroll
    for (int qb = 0; qb < 2; ++qb) {
      float pmx = fmaxf(
          fmaxf(fmaxf(fmaxf(s[qb][0][0], s[qb][0][1]), fmaxf(s[qb][0][2], s[qb][0][3])),
                fmaxf(fmaxf(s[qb][1][0], s[qb][1][1]), fmaxf(s[qb][1][2], s[qb][1][3]))),
          fmaxf(fmaxf(fmaxf(s[qb][2][0], s[qb][2][1]), fmaxf(s[qb][2][2], s[qb][2][3])),
                fmaxf(fmaxf(s[qb][3][0], s[qb][3][1]), fmaxf(s[qb][3][2], s[qb][3][3]))));
      pmx = fmaxf(pmx, __shfl_xor(pmx, 16));
      pmx = fmaxf(pmx, __shfl_xor(pmx, 32));
      float mold = mrun[qb];
      float mnew = fmaxf(mold, pmx);
      if (__any(mnew > mold)) {      // exact defer: skip rescale when no row max grew
        float alpha = __builtin_amdgcn_exp2f(mold - mnew);
        mrun[qb] = mnew;
        float alr[4];
        #pragma unroll
        for (int r = 0; r < 4; ++r) alr[r] = __shfl(alpha, lg*4 + r);
        #pragma unroll
        for (int nb = 0; nb < 4; ++nb)
          #pragma unroll
          for (int r = 0; r < 4; ++r) acc[qb][nb][r] *= alr[r];
        lrun[qb] *= alpha;
      }
      const float m = mrun[qb];
      float p[4][4];
      float rs = 0.f;
      #pragma unroll
      for (int nb = 0; nb < 4; ++nb) {
        #pragma unroll
        for (int r = 0; r < 4; ++r) {
          p[nb][r] = __builtin_amdgcn_exp2f(s[qb][nb][r] - m);
          rs += p[nb][r];
        }
      }
      union { bf16x8 v; unsigned int u[4]; } pk0, pk1;
      pk0.u[0] = cvt_pk_bf16(p[0][0], p[0][1]);
      pk0.u[1] = cvt_pk_bf16(p[0][2], p[0][3]);
      pk0.u[2] = cvt_pk_bf16(p[1][0], p[1][1]);
      pk0.u[3] = cvt_pk_bf16(p[1][2], p[1][3]);
      pk1.u[0] = cvt_pk_bf16(p[2][0], p[2][1]);
      pk1.u[1] = cvt_pk_bf16(p[2][2], p[2][3]);
      pk1.u[2] = cvt_pk_bf16(p[3][0], p[3][1]);
      pk1.u[3] = cvt_pk_bf16(p[3][2], p[3][3]);
      pa[qb][0] = pk0.v;
      pa[qb][1] = pk1.v;
      rs += __shfl_xor(rs, 16);
      rs += __shfl_xor(rs, 32);
      lrun[qb] += rs;
    }

    // --- PV: vf rows are kv-permuted to match pa's lane-local order
    #pragma unroll
    for (int nb = 0; nb < 4; ++nb) {
      #pragma unroll
      for (int kb = 0; kb < 2; ++kb) {
        bf16x8 vf = *(const bf16x8*)&Vb[(nb*16 + l15)*64 + (((kb*4 + lg) ^ swz) * 8)];
        acc[0][nb] = __builtin_amdgcn_mfma_f32_16x16x32_bf16(pa[0][kb], vf, acc[0][nb], 0, 0, 0);
        acc[1][nb] = __builtin_amdgcn_mfma_f32_16x16x32_bf16(pa[1][kb], vf, acc[1][nb], 0, 0, 0);
      }
    }
  }
#undef STAGE

  // epilogue: normalize and store
  #pragma unroll
  for (int qb = 0; qb < 2; ++qb) {
    float invl = 1.f / lrun[qb];
    float invr[4];
    #pragma unroll
    for (int r = 0; r < 4; ++r) invr[r] = __shfl(invl, lg*4 + r);
    #pragma unroll
    for (int r = 0; r < 4; ++r) {
      long row = (long)b*SEQ + q0 + w*32 + qb*16 + lg*4 + r;
      #pragma unroll
      for (int nb = 0; nb < 4; ++nb)
        Ao[row*D_MODEL + h*64 + nb*16 + l15] = f2b(acc[qb][nb][r] * invr[r]);
    }
  }
}

extern "C" void kernel_launch(void* const* d_in, const int* in_sizes, int n_in,
                              void* d_out, int out_size, void* d_ws, size_t ws_size,
                              hipStream_t stream) {
  const float* q   = (const float*)d_in[0];
  const float* k   = (const float*)d_in[1];
  const float* v   = (const float*)d_in[2];
  const float* w_q = (const float*)d_in[3];
  const float* b_q = (const float*)d_in[4];
  const float* w_k = (const float*)d_in[5];
  const float* b_k = (const float*)d_in[6];
  const float* w_v = (const float*)d_in[7];
  const float* b_v = (const float*)d_in[8];
  const float* w_o = (const float*)d_in[9];
  const float* b_o = (const float*)d_in[10];

  char* ws = (char*)d_ws;
  const size_t SZ  = (size_t)M_TOK * D_MODEL * 2;    // 16.78 MB
  const size_t WSZ = (size_t)D_MODEL * D_MODEL * 2;  // 2.10 MB
  unsigned short* wt  = (unsigned short*)(ws);                    // 4 weights
  unsigned short* wt3 = (unsigned short*)(ws + 3*WSZ);
  unsigned short* Qp  = (unsigned short*)(ws + 4*WSZ);
  unsigned short* Kp  = (unsigned short*)(ws + 4*WSZ + SZ);
  unsigned short* Vp  = (unsigned short*)(ws + 4*WSZ + 2*SZ);
  unsigned short* Vt  = (unsigned short*)(ws + 4*WSZ + 3*SZ);
  unsigned short* Ao  = (unsigned short*)(ws + 4*WSZ + 4*SZ);

  k_wtrans<<<dim3(32, 32, 4), dim3(32, 8), 0, stream>>>(w_q, w_k, w_v, w_o, wt);

  dim3 g3(D_MODEL/128, M_TOK/128, 3);  // (8, 64, 3)
  k_gemm_qkv<<<g3, 256, 0, stream>>>(q, k, v, wt, b_q, b_k, b_v, Qp, Kp, Vp);

  k_vtrans<<<dim3(SEQ/64, BATCH*NHEAD), 256, 0, stream>>>(Vp, Vt);
  k_attn  <<<dim3(SEQ/128, BATCH*NHEAD), 256, 0, stream>>>(Qp, Kp, Vt, Ao);

  dim3 gg(D_MODEL/128, M_TOK/128);
  k_gemm_out<<<gg, 256, 0, stream>>>(Ao, wt3, b_o, (float*)d_out);
}

// Round 9
// 399.948 us; speedup vs baseline: 1.1016x; 1.1016x over previous
//
#include <hip/hip_runtime.h>
#include <hip/hip_bf16.h>
#include <stdint.h>

#define D_MODEL 1024
#define NHEAD   16
#define BATCH   4
#define SEQ     2048
#define M_TOK   (BATCH*SEQ)   // 8192

// 0.125 * log2(e) folded into the Q projection
#define QSCALE  0.18033688011112042f

typedef __attribute__((ext_vector_type(8))) short bf16x8;
typedef __attribute__((ext_vector_type(4))) float f32x4;

static __device__ __forceinline__ unsigned short f2b(float x) {
  union { float f; unsigned int u; } a; a.f = x;
  unsigned int u = a.u;
  u += 0x7FFFu + ((u >> 16) & 1u);   // RNE
  return (unsigned short)(u >> 16);
}

static __device__ __forceinline__ unsigned int cvt_pk_bf16(float lo, float hi) {
  unsigned int r;
  asm("v_cvt_pk_bf16_f32 %0, %1, %2" : "=v"(r) : "v"(lo), "v"(hi));
  return r;
}

typedef const __attribute__((address_space(1))) unsigned int g_u32;
typedef __attribute__((address_space(3))) unsigned int l_u32;
static __device__ __forceinline__ void glds16(const void* g, void* l) {
  __builtin_amdgcn_global_load_lds((g_u32*)g, (l_u32*)l, 16, 0, 0);
}

// ---------------- weight transpose-cast (4 weights merged): W[K][N] f32 -> Wt[N][K] bf16 ----------------
__global__ void k_wtrans(const float* __restrict__ w0, const float* __restrict__ w1,
                         const float* __restrict__ w2, const float* __restrict__ w3,
                         unsigned short* __restrict__ wt) {
  __shared__ float tile[32][33];
  int z = blockIdx.z;
  const float* w = (z == 0) ? w0 : (z == 1) ? w1 : (z == 2) ? w2 : w3;
  unsigned short* out = wt + (size_t)z * D_MODEL * D_MODEL;
  int n0 = blockIdx.x * 32, k0 = blockIdx.y * 32;
  int tx = threadIdx.x;   // 0..31
  int ty = threadIdx.y;   // 0..7
  #pragma unroll
  for (int j = 0; j < 4; ++j)
    tile[ty + 8*j][tx] = w[(long)(k0 + ty + 8*j)*D_MODEL + n0 + tx];
  __syncthreads();
  #pragma unroll
  for (int j = 0; j < 4; ++j)
    out[(long)(n0 + ty + 8*j)*D_MODEL + k0 + tx] = f2b(tile[tx][ty + 8*j]);
}

// ---------------- GEMM core (m97 structure + XOR-swizzled LDS, single-buffer) ----------------
// Round-9: reverted to round-4's single-buffer 2-barrier core (24 KB) — the round-8
// dbuf (48 KB) halved blocks/CU (6->3) and made the kernel latency-bound once the
// XCD remap removed the fetch redundancy. Occupancy > within-wave overlap here.
// A_F32: A is fp32, staged raw (16B chunks, chunk^(row&7) swizzle), converted to bf16
//        between LDS read and MFMA.  Else A is bf16 (chunk^(row&3) swizzle).
// B is always bf16 [N][K] (chunk^(row&3) swizzle).
template<int A_F32, int OUT_BF16>
static __device__ __forceinline__ void gemm_body(
    const void* __restrict__ Aptr,
    const unsigned short* __restrict__ Bt,
    const float* __restrict__ bias,
    void* __restrict__ Cout,
    int Ndim, int Kdim, float scale,
    void* AsRaw, unsigned short* Bs,
    long m0, long n0)
{
  const int tid  = threadIdx.x;
  const int lane = tid & 63;
  const int w    = tid >> 6;
  const int wr   = w >> 1, wc = w & 1;
  const int l15  = lane & 15, lg = lane >> 4;

  f32x4 acc[4][4];
  #pragma unroll
  for (int i = 0; i < 4; ++i)
    #pragma unroll
    for (int j = 0; j < 4; ++j)
      #pragma unroll
      for (int c = 0; c < 4; ++c) acc[i][j][c] = 0.f;

  // staging lane decompositions
  const int r8 = lane >> 3, c8s = (lane & 7) ^ (r8 & 7);   // fp32 A: 8 rows x 8 chunks
  const int r4 = lane >> 2, c4s = (lane & 3) ^ (r4 & 3);   // bf16:  16 rows x 4 chunks

  for (int kt = 0; kt < Kdim; kt += 32) {
    if (A_F32) {
      const float* Af = (const float*)Aptr;
      #pragma unroll
      for (int j = 0; j < 4; ++j)
        glds16(Af + (m0 + w*32 + j*8 + r8) * Kdim + kt + c8s*4,
               (float*)AsRaw + (w*32 + j*8) * 32);
    } else {
      const unsigned short* Ab = (const unsigned short*)Aptr;
      #pragma unroll
      for (int j = 0; j < 2; ++j)
        glds16(Ab + (m0 + w*32 + j*16 + r4) * Kdim + kt + c4s*8,
               (unsigned short*)AsRaw + (w*32 + j*16) * 32);
    }
    #pragma unroll
    for (int j = 0; j < 2; ++j)
      glds16(Bt + (n0 + w*32 + j*16 + r4) * Kdim + kt + c4s*8,
             Bs + (w*32 + j*16) * 32);
    __syncthreads();

    bf16x8 af[4], bfr[4];
    #pragma unroll
    for (int m = 0; m < 4; ++m) {
      if (A_F32) {
        const float* base = (const float*)AsRaw + (wr*64 + m*16 + l15) * 32;
        f32x4 lo = *(const f32x4*)(base + (((2*lg    ) ^ (l15 & 7)) * 4));
        f32x4 hi = *(const f32x4*)(base + (((2*lg + 1) ^ (l15 & 7)) * 4));
        union { bf16x8 v; unsigned int u[4]; } tmpu;
        tmpu.u[0] = cvt_pk_bf16(lo[0], lo[1]);
        tmpu.u[1] = cvt_pk_bf16(lo[2], lo[3]);
        tmpu.u[2] = cvt_pk_bf16(hi[0], hi[1]);
        tmpu.u[3] = cvt_pk_bf16(hi[2], hi[3]);
        af[m] = tmpu.v;
      } else {
        af[m] = *(const bf16x8*)((const unsigned short*)AsRaw +
                 (wr*64 + m*16 + l15) * 32 + ((lg ^ (l15 & 3)) * 8));
      }
    }
    #pragma unroll
    for (int n = 0; n < 4; ++n)
      bfr[n] = *(const bf16x8*)&Bs[(wc*64 + n*16 + l15) * 32 + ((lg ^ (l15 & 3)) * 8)];
    #pragma unroll
    for (int m = 0; m < 4; ++m)
      #pragma unroll
      for (int n = 0; n < 4; ++n)
        acc[m][n] = __builtin_amdgcn_mfma_f32_16x16x32_bf16(af[m], bfr[n], acc[m][n], 0, 0, 0);
    __syncthreads();
  }

  #pragma unroll
  for (int m = 0; m < 4; ++m) {
    #pragma unroll
    for (int r = 0; r < 4; ++r) {
      long row = m0 + wr*64 + m*16 + lg*4 + r;
      #pragma unroll
      for (int n = 0; n < 4; ++n) {
        long col = n0 + wc*64 + n*16 + l15;
        float v = (acc[m][n][r] + bias[col]) * scale;
        if (OUT_BF16) ((unsigned short*)Cout)[row * Ndim + col] = f2b(v);
        else          ((float*)Cout)[row * Ndim + col] = v;
      }
    }
  }
}

// XCD-clustering remap for an (8 n-blocks) x (64 m-rows) grid:
// all 8 n-blocks of one m-row get the same lb%8 -> same XCD -> A-panel L2-shared.
static __device__ __forceinline__ void xcd_remap_8x64(int& m, int& n) {
  int lb = blockIdx.x + (blockIdx.y << 3);   // 0..511
  int xcd = lb & 7, i = lb >> 3;             // i: 0..63
  m = (xcd << 3) | (i >> 3);                 // 8 m-rows per XCD
  n = i & 7;
}

// merged Q/K/V projection from raw fp32 inputs: blockIdx.z selects which
__global__ __launch_bounds__(256) void k_gemm_qkv(
    const float* __restrict__ q, const float* __restrict__ k, const float* __restrict__ v,
    const unsigned short* __restrict__ wt,
    const float* __restrict__ b_q, const float* __restrict__ b_k, const float* __restrict__ b_v,
    unsigned short* __restrict__ Qp, unsigned short* __restrict__ Kp, unsigned short* __restrict__ Vp)
{
  __shared__ float          Asf[128*32];   // 16 KB
  __shared__ unsigned short Bs [128*32];   //  8 KB
  int z = blockIdx.z;
  const float* A           = (z == 0) ? q : (z == 1) ? k : v;
  const unsigned short* Bt = wt + (size_t)z * D_MODEL * D_MODEL;
  const float* bias        = (z == 0) ? b_q : (z == 1) ? b_k : b_v;
  unsigned short* Cout     = (z == 0) ? Qp : (z == 1) ? Kp : Vp;
  float scale              = (z == 0) ? QSCALE : 1.f;
  int m, n; xcd_remap_8x64(m, n);
  gemm_body<1, 1>(A, Bt, bias, Cout, D_MODEL, D_MODEL, scale, Asf, Bs,
                  (long)m * 128, (long)n * 128);
}

__global__ __launch_bounds__(256) void k_gemm_out(
    const unsigned short* __restrict__ A, const unsigned short* __restrict__ Bt,
    const float* __restrict__ bias, float* __restrict__ Cout)
{
  __shared__ unsigned short As16[128*32];  // 8 KB
  __shared__ unsigned short Bs  [128*32];  // 8 KB
  int m, n; xcd_remap_8x64(m, n);
  gemm_body<0, 0>(A, Bt, bias, Cout, D_MODEL, D_MODEL, 1.f, As16, Bs,
                  (long)m * 128, (long)n * 128);
}

// ---------------- V transpose per head, with kv permuted within 32-blocks ----------------
// Vt[(bh*64+d)][t0 + p] = Vp[b, kv = t0 + perm(p), h*64+d],
// perm(p) = (p&32) + 16*((p>>2)&1) + 4*((p>>3)&3) + (p&3)  — matches PV fragment order.
__global__ void k_vtrans(const unsigned short* __restrict__ Vp, unsigned short* __restrict__ Vt) {
  __shared__ unsigned short tile[64][72];
  int bh = blockIdx.y;
  int b = bh >> 4, h = bh & 15;
  int t0 = blockIdx.x * 64;
  int tid = threadIdx.x;
  #pragma unroll
  for (int p = 0; p < 2; ++p) {
    int idx = p*256 + tid;
    int tr = idx >> 3, c8 = (idx & 7) * 8;
    *(int4*)&tile[tr][c8] =
        *(const int4*)&Vp[((long)b*SEQ + t0 + tr)*D_MODEL + h*64 + c8];
  }
  __syncthreads();
  #pragma unroll
  for (int p = 0; p < 2; ++p) {
    int idx = p*256 + tid;
    int d = idx >> 3, c8 = (idx & 7) * 8;
    unsigned short tmp[8];
    #pragma unroll
    for (int j = 0; j < 8; ++j) {
      int pos = c8 + j;
      int src = (pos & 32) + (((pos >> 2) & 1) << 4) + (((pos >> 3) & 3) << 2) + (pos & 3);
      tmp[j] = tile[src][d];
    }
    *(int4*)&Vt[((long)bh*64 + d)*SEQ + t0 + c8] = *(int4*)tmp;
  }
}

// ---------------- flash attention: swapped QK^T, lane-local P->PV, dbuf glds16 staging ----------------
// Q pre-scaled by QSCALE -> S directly in exp2 domain.
__global__ __launch_bounds__(256) void k_attn(
    const unsigned short* __restrict__ Qp,
    const unsigned short* __restrict__ Kp,
    const unsigned short* __restrict__ Vt,
    unsigned short* __restrict__ Ao)
{
  __shared__ unsigned short KV[2][2][64*64];   // [buf][K/V][row*64+col], 32 KB total
  const int tid = threadIdx.x;
  const int lane = tid & 63;
  const int w = tid >> 6;
  // XCD-cluster remap: the 16 q-blocks of one (b,h) share K/V (1 MB) -> same XCD;
  // 8 heads/XCD x (K+V 1 MB) = 4 MB = L2 size.
  int lb = blockIdx.x + (blockIdx.y << 4);     // 0..1023
  int xcd = lb & 7, li = lb >> 3;              // li: 0..127
  const int bh = (xcd << 3) | (li >> 4);       // 0..63
  const int qblk = li & 15;
  const int b = bh >> 4, h = bh & 15;
  const int q0 = qblk * 128;
  const int l15 = lane & 15, lg = lane >> 4;
  const int swz = l15 & 7;

  // Q fragments (B-operand of swapped QK^T): q row = w*32 + qb*16 + l15
  bf16x8 qf[2][2];
  #pragma unroll
  for (int qb = 0; qb < 2; ++qb) {
    const long qrow = (long)b*SEQ + q0 + w*32 + qb*16 + l15;
    #pragma unroll
    for (int kb = 0; kb < 2; ++kb)
      qf[qb][kb] = *(const bf16x8*)&Qp[qrow*D_MODEL + h*64 + kb*32 + lg*8];
  }

  f32x4 acc[2][4];
  float mrun[2], lrun[2];
  #pragma unroll
  for (int qb = 0; qb < 2; ++qb) {
    #pragma unroll
    for (int nb = 0; nb < 4; ++nb)
      #pragma unroll
      for (int c = 0; c < 4; ++c) acc[qb][nb][c] = 0.f;
    mrun[qb] = -1e30f; lrun[qb] = 0.f;
  }

  // glds16 staging: wave w stages rows w*16..w*16+15; lane i -> row +(i>>3), phys chunk i&7,
  // source chunk (i&7)^((i>>3)&7)  (LDS slot (row,p) holds global chunk p^(row&7))
  const int sr = lane >> 3;
  const int sc = (lane & 7) ^ (sr & 7);
  const unsigned short* Kg = Kp + ((long)b*SEQ + w*16 + sr) * D_MODEL + h*64 + sc*8;
  const unsigned short* Vg = Vt + ((long)bh*64 + w*16 + sr) * SEQ + sc*8;

  const int NT = SEQ / 64;

#define STAGE(t, buf) do {                                              \
    unsigned short* Kb_ = &KV[(buf)][0][0] + w*16*64;                   \
    unsigned short* Vb_ = &KV[(buf)][1][0] + w*16*64;                   \
    glds16(Kg + (long)(t)*64*D_MODEL,                   Kb_);           \
    glds16(Kg + (long)(t)*64*D_MODEL + 8L*D_MODEL,      Kb_ + 8*64);    \
    glds16(Vg + (t)*64,                                 Vb_);           \
    glds16(Vg + (t)*64 + 8*SEQ,                         Vb_ + 8*64);    \
  } while (0)

  STAGE(0, 0);

  for (int t = 0; t < NT; ++t) {
    __syncthreads();                 // drains vmcnt -> buf[t&1] staged; all waves past t-1 reads
    if (t + 1 < NT) STAGE(t + 1, (t + 1) & 1);
    const unsigned short* Kb = &KV[t & 1][0][0];
    const unsigned short* Vb = &KV[t & 1][1][0];

    // --- QK^T (swapped): s[qb][nb][r] = S[q=l15][k=16nb+4lg+r]
    f32x4 s[2][4];
    #pragma unroll
    for (int qb = 0; qb < 2; ++qb)
      #pragma unroll
      for (int nb = 0; nb < 4; ++nb)
        #pragma unroll
        for (int c = 0; c < 4; ++c) s[qb][nb][c] = 0.f;
    #pragma unroll
    for (int nb = 0; nb < 4; ++nb) {
      #pragma unroll
      for (int kb = 0; kb < 2; ++kb) {
        bf16x8 kf = *(const bf16x8*)&Kb[(nb*16 + l15)*64 + (((kb*4 + lg) ^ swz) * 8)];
        s[0][nb] = __builtin_amdgcn_mfma_f32_16x16x32_bf16(kf, qf[0][kb], s[0][nb], 0, 0, 0);
        s[1][nb] = __builtin_amdgcn_mfma_f32_16x16x32_bf16(kf, qf[1][kb], s[1][nb], 0, 0, 0);
      }
    }

    // --- softmax (exp2 domain) + lane-local pack into PV A-fragments
    bf16x8 pa[2][2];
    #pragma unroll
    for (int qb = 0; qb < 2; ++qb) {
      float pmx = fmaxf(
          fmaxf(fmaxf(fmaxf(s[qb][0][0], s[qb][0][1]), fmaxf(s[qb][0][2], s[qb][0][3])),
                fmaxf(fmaxf(s[qb][1][0], s[qb][1][1]), fmaxf(s[qb][1][2], s[qb][1][3]))),
          fmaxf(fmaxf(fmaxf(s[qb][2][0], s[qb][2][1]), fmaxf(s[qb][2][2], s[qb][2][3])),
                fmaxf(fmaxf(s[qb][3][0], s[qb][3][1]), fmaxf(s[qb][3][2], s[qb][3][3]))));
      pmx = fmaxf(pmx, __shfl_xor(pmx, 16));
      pmx = fmaxf(pmx, __shfl_xor(pmx, 32));
      float mold = mrun[qb];
      float mnew = fmaxf(mold, pmx);
      if (__any(mnew > mold)) {      // exact defer: skip rescale when no row max grew
        float alpha = __builtin_amdgcn_exp2f(mold - mnew);
        mrun[qb] = mnew;
        float alr[4];
        #pragma unroll
        for (int r = 0; r < 4; ++r) alr[r] = __shfl(alpha, lg*4 + r);
        #pragma unroll
        for (int nb = 0; nb < 4; ++nb)
          #pragma unroll
          for (int r = 0; r < 4; ++r) acc[qb][nb][r] *= alr[r];
        lrun[qb] *= alpha;
      }
      const float m = mrun[qb];
      float p[4][4];
      float rs = 0.f;
      #pragma unroll
      for (int nb = 0; nb < 4; ++nb) {
        #pragma unroll
        for (int r = 0; r < 4; ++r) {
          p[nb][r] = __builtin_amdgcn_exp2f(s[qb][nb][r] - m);
          rs += p[nb][r];
        }
      }
      union { bf16x8 v; unsigned int u[4]; } pk0, pk1;
      pk0.u[0] = cvt_pk_bf16(p[0][0], p[0][1]);
      pk0.u[1] = cvt_pk_bf16(p[0][2], p[0][3]);
      pk0.u[2] = cvt_pk_bf16(p[1][0], p[1][1]);
      pk0.u[3] = cvt_pk_bf16(p[1][2], p[1][3]);
      pk1.u[0] = cvt_pk_bf16(p[2][0], p[2][1]);
      pk1.u[1] = cvt_pk_bf16(p[2][2], p[2][3]);
      pk1.u[2] = cvt_pk_bf16(p[3][0], p[3][1]);
      pk1.u[3] = cvt_pk_bf16(p[3][2], p[3][3]);
      pa[qb][0] = pk0.v;
      pa[qb][1] = pk1.v;
      rs += __shfl_xor(rs, 16);
      rs += __shfl_xor(rs, 32);
      lrun[qb] += rs;
    }

    // --- PV: vf rows are kv-permuted to match pa's lane-local order
    #pragma unroll
    for (int nb = 0; nb < 4; ++nb) {
      #pragma unroll
      for (int kb = 0; kb < 2; ++kb) {
        bf16x8 vf = *(const bf16x8*)&Vb[(nb*16 + l15)*64 + (((kb*4 + lg) ^ swz) * 8)];
        acc[0][nb] = __builtin_amdgcn_mfma_f32_16x16x32_bf16(pa[0][kb], vf, acc[0][nb], 0, 0, 0);
        acc[1][nb] = __builtin_amdgcn_mfma_f32_16x16x32_bf16(pa[1][kb], vf, acc[1][nb], 0, 0, 0);
      }
    }
  }
#undef STAGE

  // epilogue: normalize and store
  #pragma unroll
  for (int qb = 0; qb < 2; ++qb) {
    float invl = 1.f / lrun[qb];
    float invr[4];
    #pragma unroll
    for (int r = 0; r < 4; ++r) invr[r] = __shfl(invl, lg*4 + r);
    #pragma unroll
    for (int r = 0; r < 4; ++r) {
      long row = (long)b*SEQ + q0 + w*32 + qb*16 + lg*4 + r;
      #pragma unroll
      for (int nb = 0; nb < 4; ++nb)
        Ao[row*D_MODEL + h*64 + nb*16 + l15] = f2b(acc[qb][nb][r] * invr[r]);
    }
  }
}

extern "C" void kernel_launch(void* const* d_in, const int* in_sizes, int n_in,
                              void* d_out, int out_size, void* d_ws, size_t ws_size,
                              hipStream_t stream) {
  const float* q   = (const float*)d_in[0];
  const float* k   = (const float*)d_in[1];
  const float* v   = (const float*)d_in[2];
  const float* w_q = (const float*)d_in[3];
  const float* b_q = (const float*)d_in[4];
  const float* w_k = (const float*)d_in[5];
  const float* b_k = (const float*)d_in[6];
  const float* w_v = (const float*)d_in[7];
  const float* b_v = (const float*)d_in[8];
  const float* w_o = (const float*)d_in[9];
  const float* b_o = (const float*)d_in[10];

  char* ws = (char*)d_ws;
  const size_t SZ  = (size_t)M_TOK * D_MODEL * 2;    // 16.78 MB
  const size_t WSZ = (size_t)D_MODEL * D_MODEL * 2;  // 2.10 MB
  unsigned short* wt  = (unsigned short*)(ws);                    // 4 weights
  unsigned short* wt3 = (unsigned short*)(ws + 3*WSZ);
  unsigned short* Qp  = (unsigned short*)(ws + 4*WSZ);
  unsigned short* Kp  = (unsigned short*)(ws + 4*WSZ + SZ);
  unsigned short* Vp  = (unsigned short*)(ws + 4*WSZ + 2*SZ);
  unsigned short* Vt  = (unsigned short*)(ws + 4*WSZ + 3*SZ);
  unsigned short* Ao  = (unsigned short*)(ws + 4*WSZ + 4*SZ);

  k_wtrans<<<dim3(32, 32, 4), dim3(32, 8), 0, stream>>>(w_q, w_k, w_v, w_o, wt);

  dim3 g3(D_MODEL/128, M_TOK/128, 3);  // (8, 64, 3)
  k_gemm_qkv<<<g3, 256, 0, stream>>>(q, k, v, wt, b_q, b_k, b_v, Qp, Kp, Vp);

  k_vtrans<<<dim3(SEQ/64, BATCH*NHEAD), 256, 0, stream>>>(Vp, Vt);
  k_attn  <<<dim3(SEQ/128, BATCH*NHEAD), 256, 0, stream>>>(Qp, Kp, Vt, Ao);

  dim3 gg(D_MODEL/128, M_TOK/128);
  k_gemm_out<<<gg, 256, 0, stream>>>(Ao, wt3, b_o, (float*)d_out);
}

// Round 11
// 363.933 us; speedup vs baseline: 1.2107x; 1.0990x over previous
//
#include <hip/hip_runtime.h>
#include <hip/hip_bf16.h>
#include <stdint.h>

#define D_MODEL 1024
#define NHEAD   16
#define BATCH   4
#define SEQ     2048
#define M_TOK   (BATCH*SEQ)   // 8192

// 0.125 * log2(e) folded into the Q projection
#define QSCALE  0.18033688011112042f

typedef __attribute__((ext_vector_type(8))) short bf16x8;
typedef __attribute__((ext_vector_type(4))) float f32x4;

static __device__ __forceinline__ unsigned short f2b(float x) {
  union { float f; unsigned int u; } a; a.f = x;
  unsigned int u = a.u;
  u += 0x7FFFu + ((u >> 16) & 1u);   // RNE
  return (unsigned short)(u >> 16);
}

static __device__ __forceinline__ unsigned int cvt_pk_bf16(float lo, float hi) {
  unsigned int r;
  asm("v_cvt_pk_bf16_f32 %0, %1, %2" : "=v"(r) : "v"(lo), "v"(hi));
  return r;
}

typedef const __attribute__((address_space(1))) unsigned int g_u32;
typedef __attribute__((address_space(3))) unsigned int l_u32;
static __device__ __forceinline__ void glds16(const void* g, void* l) {
  __builtin_amdgcn_global_load_lds((g_u32*)g, (l_u32*)l, 16, 0, 0);
}

// ---------------- cast fp32 -> bf16 (q,k,v merged) ----------------
__global__ void k_cast(const float* __restrict__ q, const float* __restrict__ k,
                       const float* __restrict__ v,
                       unsigned short* __restrict__ qo, unsigned short* __restrict__ ko,
                       unsigned short* __restrict__ vo, int n4) {
  int i = blockIdx.x * 256 + threadIdx.x;
  if (i >= n4) return;
  const float* src = (blockIdx.y == 0) ? q : (blockIdx.y == 1) ? k : v;
  unsigned short* dst = (blockIdx.y == 0) ? qo : (blockIdx.y == 1) ? ko : vo;
  float4 f = reinterpret_cast<const float4*>(src)[i];
  ushort4 o;
  o.x = f2b(f.x); o.y = f2b(f.y); o.z = f2b(f.z); o.w = f2b(f.w);
  reinterpret_cast<ushort4*>(dst)[i] = o;
}

// ---------------- weight transpose-cast (4 weights merged): W[K][N] f32 -> Wt[N][K] bf16 ----------------
__global__ void k_wtrans(const float* __restrict__ w0, const float* __restrict__ w1,
                         const float* __restrict__ w2, const float* __restrict__ w3,
                         unsigned short* __restrict__ wt) {
  __shared__ float tile[32][33];
  int z = blockIdx.z;
  const float* w = (z == 0) ? w0 : (z == 1) ? w1 : (z == 2) ? w2 : w3;
  unsigned short* out = wt + (size_t)z * D_MODEL * D_MODEL;
  int n0 = blockIdx.x * 32, k0 = blockIdx.y * 32;
  int tx = threadIdx.x;   // 0..31
  int ty = threadIdx.y;   // 0..7
  #pragma unroll
  for (int j = 0; j < 4; ++j)
    tile[ty + 8*j][tx] = w[(long)(k0 + ty + 8*j)*D_MODEL + n0 + tx];
  __syncthreads();
  #pragma unroll
  for (int j = 0; j < 4; ++j)
    out[(long)(n0 + ty + 8*j)*D_MODEL + k0 + tx] = f2b(tile[tx][ty + 8*j]);
}

// ---------------- GEMM core: bf16 A and B, single-buffer, corrected XOR swizzle ----------------
// LDS tile rows are 64 B (32 bf16). Bank slot of (row, chunk) = 16*(row&1) + 4*chunk.
// f(row) = (row>>1)&3 makes rows 0..7 cover all 8 slots -> 2-way aliasing (free).
// (Round-9's f(row)=row&3 repeated slots every 4 rows -> 4-way conflict, 9.4M cycles.)
// LDS slot (row, c) holds global chunk c ^ f(row): staged via pre-swizzled source,
// read back with the same XOR.
template<int OUT_BF16>
static __device__ __forceinline__ void gemm_body(
    const unsigned short* __restrict__ A,
    const unsigned short* __restrict__ Bt,
    const float* __restrict__ bias,
    void* __restrict__ Cout,
    int Ndim, int Kdim, float scale,
    unsigned short* As, unsigned short* Bs,
    long m0, long n0)
{
  const int tid  = threadIdx.x;
  const int lane = tid & 63;
  const int w    = tid >> 6;
  const int wr   = w >> 1, wc = w & 1;
  const int l15  = lane & 15, lg = lane >> 4;
  const int rsw  = (l15 >> 1) & 3;          // read-side XOR

  f32x4 acc[4][4];
  #pragma unroll
  for (int i = 0; i < 4; ++i)
    #pragma unroll
    for (int j = 0; j < 4; ++j)
      #pragma unroll
      for (int c = 0; c < 4; ++c) acc[i][j][c] = 0.f;

  // staging: lane i -> row (i>>2), phys chunk (i&3); source chunk = (i&3) ^ f(row)
  const int r4  = lane >> 2;
  const int c4s = (lane & 3) ^ ((lane >> 3) & 3);

  for (int kt = 0; kt < Kdim; kt += 32) {
    #pragma unroll
    for (int j = 0; j < 2; ++j) {
      glds16(A  + (m0 + w*32 + j*16 + r4) * Kdim + kt + c4s*8, As + (w*32 + j*16) * 32);
      glds16(Bt + (n0 + w*32 + j*16 + r4) * Kdim + kt + c4s*8, Bs + (w*32 + j*16) * 32);
    }
    __syncthreads();

    bf16x8 af[4], bfr[4];
    #pragma unroll
    for (int m = 0; m < 4; ++m)
      af[m] = *(const bf16x8*)&As[(wr*64 + m*16 + l15) * 32 + ((lg ^ rsw) * 8)];
    #pragma unroll
    for (int n = 0; n < 4; ++n)
      bfr[n] = *(const bf16x8*)&Bs[(wc*64 + n*16 + l15) * 32 + ((lg ^ rsw) * 8)];
    #pragma unroll
    for (int m = 0; m < 4; ++m)
      #pragma unroll
      for (int n = 0; n < 4; ++n)
        acc[m][n] = __builtin_amdgcn_mfma_f32_16x16x32_bf16(af[m], bfr[n], acc[m][n], 0, 0, 0);
    __syncthreads();
  }

  #pragma unroll
  for (int m = 0; m < 4; ++m) {
    #pragma unroll
    for (int r = 0; r < 4; ++r) {
      long row = m0 + wr*64 + m*16 + lg*4 + r;
      #pragma unroll
      for (int n = 0; n < 4; ++n) {
        long col = n0 + wc*64 + n*16 + l15;
        float v = (acc[m][n][r] + bias[col]) * scale;
        if (OUT_BF16) ((unsigned short*)Cout)[row * Ndim + col] = f2b(v);
        else          ((float*)Cout)[row * Ndim + col] = v;
      }
    }
  }
}

// XCD-clustering remap for an (8 n-blocks) x (64 m-rows) grid:
// all 8 n-blocks of one m-row get the same lb%8 -> same XCD -> A-panel L2-shared.
static __device__ __forceinline__ void xcd_remap_8x64(int& m, int& n) {
  int lb = blockIdx.x + (blockIdx.y << 3);   // 0..511
  int xcd = lb & 7, i = lb >> 3;             // i: 0..63
  m = (xcd << 3) | (i >> 3);                 // 8 m-rows per XCD
  n = i & 7;
}

// merged Q/K/V projection (bf16 inputs): blockIdx.z selects which
__global__ __launch_bounds__(256) void k_gemm_qkv(
    const unsigned short* __restrict__ qb, const unsigned short* __restrict__ kb,
    const unsigned short* __restrict__ vb, const unsigned short* __restrict__ wt,
    const float* __restrict__ b_q, const float* __restrict__ b_k, const float* __restrict__ b_v,
    unsigned short* __restrict__ Qp, unsigned short* __restrict__ Kp, unsigned short* __restrict__ Vp)
{
  __shared__ unsigned short As[128*32];    // 8 KB
  __shared__ unsigned short Bs[128*32];    // 8 KB
  int z = blockIdx.z;
  const unsigned short* A  = (z == 0) ? qb : (z == 1) ? kb : vb;
  const unsigned short* Bt = wt + (size_t)z * D_MODEL * D_MODEL;
  const float* bias        = (z == 0) ? b_q : (z == 1) ? b_k : b_v;
  unsigned short* Cout     = (z == 0) ? Qp : (z == 1) ? Kp : Vp;
  float scale              = (z == 0) ? QSCALE : 1.f;
  int m, n; xcd_remap_8x64(m, n);
  gemm_body<1>(A, Bt, bias, Cout, D_MODEL, D_MODEL, scale, As, Bs,
               (long)m * 128, (long)n * 128);
}

__global__ __launch_bounds__(256) void k_gemm_out(
    const unsigned short* __restrict__ A, const unsigned short* __restrict__ Bt,
    const float* __restrict__ bias, float* __restrict__ Cout)
{
  __shared__ unsigned short As[128*32];    // 8 KB
  __shared__ unsigned short Bs[128*32];    // 8 KB
  int m, n; xcd_remap_8x64(m, n);
  gemm_body<0>(A, Bt, bias, Cout, D_MODEL, D_MODEL, 1.f, As, Bs,
               (long)m * 128, (long)n * 128);
}

// ---------------- V transpose per head, with kv permuted within 32-blocks ----------------
// Vt[(bh*64+d)][t0 + p] = Vp[b, kv = t0 + perm(p), h*64+d],
// perm(p) = (p&32) + 16*((p>>2)&1) + 4*((p>>3)&3) + (p&3)  — matches PV fragment order.
__global__ void k_vtrans(const unsigned short* __restrict__ Vp, unsigned short* __restrict__ Vt) {
  __shared__ unsigned short tile[64][72];
  int bh = blockIdx.y;
  int b = bh >> 4, h = bh & 15;
  int t0 = blockIdx.x * 64;
  int tid = threadIdx.x;
  #pragma unroll
  for (int p = 0; p < 2; ++p) {
    int idx = p*256 + tid;
    int tr = idx >> 3, c8 = (idx & 7) * 8;
    *(int4*)&tile[tr][c8] =
        *(const int4*)&Vp[((long)b*SEQ + t0 + tr)*D_MODEL + h*64 + c8];
  }
  __syncthreads();
  #pragma unroll
  for (int p = 0; p < 2; ++p) {
    int idx = p*256 + tid;
    int d = idx >> 3, c8 = (idx & 7) * 8;
    unsigned short tmp[8];
    #pragma unroll
    for (int j = 0; j < 8; ++j) {
      int pos = c8 + j;
      int src = (pos & 32) + (((pos >> 2) & 1) << 4) + (((pos >> 3) & 3) << 2) + (pos & 3);
      tmp[j] = tile[src][d];
    }
    *(int4*)&Vt[((long)bh*64 + d)*SEQ + t0 + c8] = *(int4*)tmp;
  }
}

// ---------------- flash attention: swapped QK^T, lane-local P->PV, dbuf glds16 staging ----------------
// Q pre-scaled by QSCALE -> S directly in exp2 domain.
__global__ __launch_bounds__(256) void k_attn(
    const unsigned short* __restrict__ Qp,
    const unsigned short* __restrict__ Kp,
    const unsigned short* __restrict__ Vt,
    unsigned short* __restrict__ Ao)
{
  __shared__ unsigned short KV[2][2][64*64];   // [buf][K/V][row*64+col], 32 KB total
  const int tid = threadIdx.x;
  const int lane = tid & 63;
  const int w = tid >> 6;
  // XCD-cluster remap: the 16 q-blocks of one (b,h) share K/V (1 MB) -> same XCD;
  // 8 heads/XCD x (K+V 1 MB) = 4 MB = L2 size.
  int lb = blockIdx.x + (blockIdx.y << 4);     // 0..1023
  int xcd = lb & 7, li = lb >> 3;              // li: 0..127
  const int bh = (xcd << 3) | (li >> 4);       // 0..63
  const int qblk = li & 15;
  const int b = bh >> 4, h = bh & 15;
  const int q0 = qblk * 128;
  const int l15 = lane & 15, lg = lane >> 4;
  const int swz = l15 & 7;

  // Q fragments (B-operand of swapped QK^T): q row = w*32 + qb*16 + l15
  bf16x8 qf[2][2];
  #pragma unroll
  for (int qb = 0; qb < 2; ++qb) {
    const long qrow = (long)b*SEQ + q0 + w*32 + qb*16 + l15;
    #pragma unroll
    for (int kb = 0; kb < 2; ++kb)
      qf[qb][kb] = *(const bf16x8*)&Qp[qrow*D_MODEL + h*64 + kb*32 + lg*8];
  }

  f32x4 acc[2][4];
  float mrun[2], lrun[2];
  #pragma unroll
  for (int qb = 0; qb < 2; ++qb) {
    #pragma unroll
    for (int nb = 0; nb < 4; ++nb)
      #pragma unroll
      for (int c = 0; c < 4; ++c) acc[qb][nb][c] = 0.f;
    mrun[qb] = -1e30f; lrun[qb] = 0.f;
  }

  // glds16 staging: wave w stages rows w*16..w*16+15; lane i -> row +(i>>3), phys chunk i&7,
  // source chunk (i&7)^((i>>3)&7)  (LDS slot (row,p) holds global chunk p^(row&7))
  const int sr = lane >> 3;
  const int sc = (lane & 7) ^ (sr & 7);
  const unsigned short* Kg = Kp + ((long)b*SEQ + w*16 + sr) * D_MODEL + h*64 + sc*8;
  const unsigned short* Vg = Vt + ((long)bh*64 + w*16 + sr) * SEQ + sc*8;

  const int NT = SEQ / 64;

#define STAGE(t, buf) do {                                              \
    unsigned short* Kb_ = &KV[(buf)][0][0] + w*16*64;                   \
    unsigned short* Vb_ = &KV[(buf)][1][0] + w*16*64;                   \
    glds16(Kg + (long)(t)*64*D_MODEL,                   Kb_);           \
    glds16(Kg + (long)(t)*64*D_MODEL + 8L*D_MODEL,      Kb_ + 8*64);    \
    glds16(Vg + (t)*64,                                 Vb_);           \
    glds16(Vg + (t)*64 + 8*SEQ,                         Vb_ + 8*64);    \
  } while (0)

  STAGE(0, 0);

  for (int t = 0; t < NT; ++t) {
    __syncthreads();                 // drains vmcnt -> buf[t&1] staged; all waves past t-1 reads
    if (t + 1 < NT) STAGE(t + 1, (t + 1) & 1);
    const unsigned short* Kb = &KV[t & 1][0][0];
    const unsigned short* Vb = &KV[t & 1][1][0];

    // --- QK^T (swapped): s[qb][nb][r] = S[q=l15][k=16nb+4lg+r]
    f32x4 s[2][4];
    #pragma unroll
    for (int qb = 0; qb < 2; ++qb)
      #pragma unroll
      for (int nb = 0; nb < 4; ++nb)
        #pragma unroll
        for (int c = 0; c < 4; ++c) s[qb][nb][c] = 0.f;
    #pragma unroll
    for (int nb = 0; nb < 4; ++nb) {
      #pragma unroll
      for (int kb = 0; kb < 2; ++kb) {
        bf16x8 kf = *(const bf16x8*)&Kb[(nb*16 + l15)*64 + (((kb*4 + lg) ^ swz) * 8)];
        s[0][nb] = __builtin_amdgcn_mfma_f32_16x16x32_bf16(kf, qf[0][kb], s[0][nb], 0, 0, 0);
        s[1][nb] = __builtin_amdgcn_mfma_f32_16x16x32_bf16(kf, qf[1][kb], s[1][nb], 0, 0, 0);
      }
    }

    // --- softmax (exp2 domain) + lane-local pack into PV A-fragments
    bf16x8 pa[2][2];
    #pragma unroll
    for (int qb = 0; qb < 2; ++qb) {
      float pmx = fmaxf(
          fmaxf(fmaxf(fmaxf(s[qb][0][0], s[qb][0][1]), fmaxf(s[qb][0][2], s[qb][0][3])),
                fmaxf(fmaxf(s[qb][1][0], s[qb][1][1]), fmaxf(s[qb][1][2], s[qb][1][3]))),
          fmaxf(fmaxf(fmaxf(s[qb][2][0], s[qb][2][1]), fmaxf(s[qb][2][2], s[qb][2][3])),
                fmaxf(fmaxf(s[qb][3][0], s[qb][3][1]), fmaxf(s[qb][3][2], s[qb][3][3]))));
      pmx = fmaxf(pmx, __shfl_xor(pmx, 16));
      pmx = fmaxf(pmx, __shfl_xor(pmx, 32));
      float mold = mrun[qb];
      float mnew = fmaxf(mold, pmx);
      if (__any(mnew > mold)) {      // exact defer: skip rescale when no row max grew
        float alpha = __builtin_amdgcn_exp2f(mold - mnew);
        mrun[qb] = mnew;
        float alr[4];
        #pragma unroll
        for (int r = 0; r < 4; ++r) alr[r] = __shfl(alpha, lg*4 + r);
        #pragma unroll
        for (int nb = 0; nb < 4; ++nb)
          #pragma unroll
          for (int r = 0; r < 4; ++r) acc[qb][nb][r] *= alr[r];
        lrun[qb] *= alpha;
      }
      const float m = mrun[qb];
      float p[4][4];
      float rs = 0.f;
      #pragma unroll
      for (int nb = 0; nb < 4; ++nb) {
        #pragma unroll
        for (int r = 0; r < 4; ++r) {
          p[nb][r] = __builtin_amdgcn_exp2f(s[qb][nb][r] - m);
          rs += p[nb][r];
        }
      }
      union { bf16x8 v; unsigned int u[4]; } pk0, pk1;
      pk0.u[0] = cvt_pk_bf16(p[0][0], p[0][1]);
      pk0.u[1] = cvt_pk_bf16(p[0][2], p[0][3]);
      pk0.u[2] = cvt_pk_bf16(p[1][0], p[1][1]);
      pk0.u[3] = cvt_pk_bf16(p[1][2], p[1][3]);
      pk1.u[0] = cvt_pk_bf16(p[2][0], p[2][1]);
      pk1.u[1] = cvt_pk_bf16(p[2][2], p[2][3]);
      pk1.u[2] = cvt_pk_bf16(p[3][0], p[3][1]);
      pk1.u[3] = cvt_pk_bf16(p[3][2], p[3][3]);
      pa[qb][0] = pk0.v;
      pa[qb][1] = pk1.v;
      rs += __shfl_xor(rs, 16);
      rs += __shfl_xor(rs, 32);
      lrun[qb] += rs;
    }

    // --- PV: vf rows are kv-permuted to match pa's lane-local order
    #pragma unroll
    for (int nb = 0; nb < 4; ++nb) {
      #pragma unroll
      for (int kb = 0; kb < 2; ++kb) {
        bf16x8 vf = *(const bf16x8*)&Vb[(nb*16 + l15)*64 + (((kb*4 + lg) ^ swz) * 8)];
        acc[0][nb] = __builtin_amdgcn_mfma_f32_16x16x32_bf16(pa[0][kb], vf, acc[0][nb], 0, 0, 0);
        acc[1][nb] = __builtin_amdgcn_mfma_f32_16x16x32_bf16(pa[1][kb], vf, acc[1][nb], 0, 0, 0);
      }
    }
  }
#undef STAGE

  // epilogue: normalize and store
  #pragma unroll
  for (int qb = 0; qb < 2; ++qb) {
    float invl = 1.f / lrun[qb];
    float invr[4];
    #pragma unroll
    for (int r = 0; r < 4; ++r) invr[r] = __shfl(invl, lg*4 + r);
    #pragma unroll
    for (int r = 0; r < 4; ++r) {
      long row = (long)b*SEQ + q0 + w*32 + qb*16 + lg*4 + r;
      #pragma unroll
      for (int nb = 0; nb < 4; ++nb)
        Ao[row*D_MODEL + h*64 + nb*16 + l15] = f2b(acc[qb][nb][r] * invr[r]);
    }
  }
}

extern "C" void kernel_launch(void* const* d_in, const int* in_sizes, int n_in,
                              void* d_out, int out_size, void* d_ws, size_t ws_size,
                              hipStream_t stream) {
  const float* q   = (const float*)d_in[0];
  const float* k   = (const float*)d_in[1];
  const float* v   = (const float*)d_in[2];
  const float* w_q = (const float*)d_in[3];
  const float* b_q = (const float*)d_in[4];
  const float* w_k = (const float*)d_in[5];
  const float* b_k = (const float*)d_in[6];
  const float* w_v = (const float*)d_in[7];
  const float* b_v = (const float*)d_in[8];
  const float* w_o = (const float*)d_in[9];
  const float* b_o = (const float*)d_in[10];

  char* ws = (char*)d_ws;
  const size_t SZ  = (size_t)M_TOK * D_MODEL * 2;    // 16.78 MB
  const size_t WSZ = (size_t)D_MODEL * D_MODEL * 2;  // 2.10 MB
  unsigned short* wt  = (unsigned short*)(ws);                    // 4 weights
  unsigned short* wt3 = (unsigned short*)(ws + 3*WSZ);
  unsigned short* qb  = (unsigned short*)(ws + 4*WSZ);
  unsigned short* kb  = (unsigned short*)(ws + 4*WSZ + SZ);
  unsigned short* vb  = (unsigned short*)(ws + 4*WSZ + 2*SZ);
  unsigned short* Qp  = (unsigned short*)(ws + 4*WSZ + 3*SZ);
  unsigned short* Kp  = (unsigned short*)(ws + 4*WSZ + 4*SZ);
  unsigned short* Vp  = (unsigned short*)(ws + 4*WSZ + 5*SZ);
  unsigned short* Vt  = qb;  // qb dead after qkv GEMM
  unsigned short* Ao  = kb;  // kb dead after qkv GEMM

  const int n4 = M_TOK * D_MODEL / 4;
  k_cast<<<dim3(n4/256, 3), 256, 0, stream>>>(q, k, v, qb, kb, vb, n4);
  k_wtrans<<<dim3(32, 32, 4), dim3(32, 8), 0, stream>>>(w_q, w_k, w_v, w_o, wt);

  dim3 g3(D_MODEL/128, M_TOK/128, 3);  // (8, 64, 3)
  k_gemm_qkv<<<g3, 256, 0, stream>>>(qb, kb, vb, wt, b_q, b_k, b_v, Qp, Kp, Vp);

  k_vtrans<<<dim3(SEQ/64, BATCH*NHEAD), 256, 0, stream>>>(Vp, Vt);
  k_attn  <<<dim3(SEQ/128, BATCH*NHEAD), 256, 0, stream>>>(Qp, Kp, Vt, Ao);

  dim3 gg(D_MODEL/128, M_TOK/128);
  k_gemm_out<<<gg, 256, 0, stream>>>(Ao, wt3, b_o, (float*)d_out);
}